// Round 1
// baseline (198.484 us; speedup 1.0000x reference)
//
#include <hip/hip_runtime.h>
#include <stdint.h>

#define NF 27
#define ND 128
#define OUTW 479          // 128 + 27*26/2
#define LDSROW 136        // 128 + 8 pad (ushort units); 272 B rows -> bank spread
#define WAVES 4

typedef float f32x4 __attribute__((ext_vector_type(4)));
typedef short s16x8 __attribute__((ext_vector_type(8)));

__device__ __forceinline__ unsigned short f2bf(float x) {
    union { float f; uint32_t u; } c; c.f = x;
    uint32_t u = c.u;
    u += 0x7fffu + ((u >> 16) & 1u);   // RNE round to bf16
    return (unsigned short)(u >> 16);
}

__global__ __launch_bounds__(256) void dot_interact_kernel(
    const float* __restrict__ feat,
    const float* __restrict__ bottom,
    float* __restrict__ out, int B)
{
    __shared__ unsigned short smem[WAVES][32 * LDSROW];   // 34,816 B/block
    const int tid  = threadIdx.x;
    const int w    = tid >> 6;
    const int lane = tid & 63;
    const int b    = blockIdx.x * WAVES + w;
    unsigned short* sm = smem[w];

    if (b < B) {
        // ---- stage: 27*128 f32 -> bf16 LDS rows 0..26; rows 27..31 zeroed ----
        const float4* f4 = (const float4*)(feat + (size_t)b * (NF * ND));
        #pragma unroll
        for (int t = 0; t < 16; ++t) {
            int fi  = lane + 64 * t;          // 0..1023 covers 32 rows * 32 float4
            int row = fi >> 5;
            int c4  = fi & 31;
            uint32_t lo = 0, hi = 0;
            if (fi < 864) {                   // 27 rows * 32 float4 of real data
                float4 v = f4[fi];
                lo = (uint32_t)f2bf(v.x) | ((uint32_t)f2bf(v.y) << 16);
                hi = (uint32_t)f2bf(v.z) | ((uint32_t)f2bf(v.w) << 16);
            }
            *(uint2*)(&sm[row * LDSROW + c4 * 4]) = make_uint2(lo, hi);
        }
    }
    __syncthreads();
    if (b >= B) return;

    // ---- Gram = F * F^T via mfma_f32_16x16x32_bf16 ----
    // A-frag(row block) == B-frag(col block) for a Gram matrix: one load, both uses.
    f32x4 acc00 = {0.f,0.f,0.f,0.f};
    f32x4 acc10 = {0.f,0.f,0.f,0.f};
    f32x4 acc11 = {0.f,0.f,0.f,0.f};
    const int rsel = lane & 15;
    const int ksel = (lane >> 4) * 8;
    #pragma unroll
    for (int ks = 0; ks < 4; ++ks) {
        int k0 = ks * 32 + ksel;
        s16x8 fr0 = *(const s16x8*)(&sm[(rsel     ) * LDSROW + k0]);
        s16x8 fr1 = *(const s16x8*)(&sm[(rsel + 16) * LDSROW + k0]);
        acc00 = __builtin_amdgcn_mfma_f32_16x16x32_bf16(fr0, fr0, acc00, 0, 0, 0);
        acc10 = __builtin_amdgcn_mfma_f32_16x16x32_bf16(fr1, fr0, acc10, 0, 0, 0);
        acc11 = __builtin_amdgcn_mfma_f32_16x16x32_bf16(fr1, fr1, acc11, 0, 0, 0);
    }

    float* ob = out + (size_t)b * OUTW;

    // ---- bottom_mlp_out copy (coalesced) ----
    const float* bb = bottom + (size_t)b * ND;
    ob[lane]      = bb[lane];
    ob[lane + 64] = bb[lane + 64];

    // ---- tril scatter: C/D layout col=lane&15, row=(lane>>4)*4+e ----
    const int jj = lane & 15;
    const int r0 = (lane >> 4) * 4;
    #pragma unroll
    for (int e = 0; e < 4; ++e) {
        {   // tile (0,0): i in 0..15, j in 0..15
            int i = r0 + e, j = jj;
            if (j < i) ob[128 + (i * (i - 1)) / 2 + j] = acc00[e];
        }
        {   // tile (1,0): i in 16..31, j in 0..15  (j<i always)
            int i = r0 + e + 16, j = jj;
            if (i < NF) ob[128 + (i * (i - 1)) / 2 + j] = acc10[e];
        }
        {   // tile (1,1): i in 16..31, j in 16..31
            int i = r0 + e + 16, j = jj + 16;
            if (i < NF && j < i) ob[128 + (i * (i - 1)) / 2 + j] = acc11[e];
        }
    }
}

extern "C" void kernel_launch(void* const* d_in, const int* in_sizes, int n_in,
                              void* d_out, int out_size, void* d_ws, size_t ws_size,
                              hipStream_t stream) {
    const float* feat   = (const float*)d_in[0];
    const float* bottom = (const float*)d_in[1];
    float* out          = (float*)d_out;
    const int B = in_sizes[0] / (NF * ND);
    const int grid = (B + WAVES - 1) / WAVES;
    dot_interact_kernel<<<grid, 256, 0, stream>>>(feat, bottom, out, B);
}